// Round 7
// baseline (1560.464 us; speedup 1.0000x reference)
//
#include <hip/hip_runtime.h>
#include <hip/hip_bf16.h>
#include <cstdint>

#define CCH 48
#define DD 128
#define HH 128
#define WW 128
#define NVOX (DD*HH*WW)        // 2,097,152 voxels
#define NPTS 2097152
// Bricks: 8x4x4 voxels (x,y,z); halo 9x5x5 = 225 voxels (21,600 B LDS)
#define NBINS 16384            // bx:16, by:32, bz:32
#define BRICK_VOX 225
#define SLOTS 160              // fixed bin capacity (avg 128, +2.8 sigma)
#define OVF_CAP 65536

typedef unsigned int uint;
typedef unsigned short ushort_t;

__device__ __forceinline__ ushort_t f2bf_rne(float f) {
    uint u = __float_as_uint(f);
    uint r = (u + 0x7fffu + ((u >> 16) & 1u)) >> 16;
    return (ushort_t)r;
}

struct PtGeo {
    int x0, y0, z0, x1, y1, z1;
    float wx, wy, wz;
};
__device__ __forceinline__ PtGeo pt_geo3(float px, float py, float pz) {
    PtGeo g;
    const float ix = (px + 1.0f) * 63.5f;
    const float iy = (py + 1.0f) * 63.5f;
    const float iz = (pz + 1.0f) * 63.5f;
    const float xf = floorf(ix), yf = floorf(iy), zf = floorf(iz);
    g.wx = ix - xf; g.wy = iy - yf; g.wz = iz - zf;
    int x0 = (int)xf, y0 = (int)yf, z0 = (int)zf;
    g.x0 = min(max(x0,0), WW-1); g.x1 = min(max(x0+1,0), WW-1);
    g.y0 = min(max(y0,0), HH-1); g.y1 = min(max(y0+1,0), HH-1);
    g.z0 = min(max(z0,0), DD-1); g.z1 = min(max(z0+1,0), DD-1);
    return g;
}
__device__ __forceinline__ PtGeo pt_geo(const float* __restrict__ pts, int n) {
    return pt_geo3(pts[n*3+0], pts[n*3+1], pts[n*3+2]);
}
// brick 8x4x4: bin = ((bz*32)+by)*16 + bx
__device__ __forceinline__ int pt_bin(const PtGeo& g) {
    return (((g.z0 >> 2) * 32 + (g.y0 >> 2)) * 16) + (g.x0 >> 3);
}

// ---------------------------------------------------------------------------
// Kernel 1 (R1 structure, best measured): 1 voxel/thread, coalesced
// channel-major NT reads, 96B contiguous bf16 store.
// ---------------------------------------------------------------------------
__global__ __launch_bounds__(256) void fuse_transpose_kernel(
    const float* __restrict__ k0, const float* __restrict__ former,
    ushort_t* __restrict__ grid_t)
{
    const int v = blockIdx.x * 256 + threadIdx.x;
    float vals[CCH];
#pragma unroll
    for (int c = 0; c < CCH; ++c) {
        const size_t off = (size_t)c * NVOX + v;
        vals[c] = __builtin_nontemporal_load(k0 + off)
                + __builtin_nontemporal_load(former + off);
    }
    uint4* dst = reinterpret_cast<uint4*>(grid_t + (size_t)v * CCH);
#pragma unroll
    for (int i = 0; i < 6; ++i) {
        uint4 u;
        u.x = (uint)f2bf_rne(vals[i*8+0]) | ((uint)f2bf_rne(vals[i*8+1]) << 16);
        u.y = (uint)f2bf_rne(vals[i*8+2]) | ((uint)f2bf_rne(vals[i*8+3]) << 16);
        u.z = (uint)f2bf_rne(vals[i*8+4]) | ((uint)f2bf_rne(vals[i*8+5]) << 16);
        u.w = (uint)f2bf_rne(vals[i*8+6]) | ((uint)f2bf_rne(vals[i*8+7]) << 16);
        dst[i] = u;
    }
}

// ---------------------------------------------------------------------------
// Single-pass binning: fixed SLOTS per bin, overflow -> small list.
// Output values are identical for lds/overflow paths (same grid, same FMA
// order) so the atomic race does not affect the result.
// ---------------------------------------------------------------------------
__global__ __launch_bounds__(256) void scatter_direct(
    const float* __restrict__ pts, uint* __restrict__ count,
    uint* __restrict__ order, uint* __restrict__ ovf_cnt, uint* __restrict__ ovf)
{
    const int n = blockIdx.x * 256 + threadIdx.x;
    if (n >= NPTS) return;
    const PtGeo g = pt_geo(pts, n);
    const int b = pt_bin(g);
    const uint pos = atomicAdd(&count[b], 1u);
    if (pos < SLOTS) {
        order[b * SLOTS + pos] = (uint)n;
    } else {
        const uint op = atomicAdd(ovf_cnt, 1u);
        if (op < OVF_CAP) ovf[op] = (uint)n;
    }
}

// ---------------------------------------------------------------------------
// Kernel 2 v6: one block per 8x4x4 bin. Stage halo brick (225 vox x 96B =
// 21,600 B LDS, 7 blocks/CU), first point's loads hoisted above the barrier,
// 2-corner load batches to keep VGPR under the (256,6) cap.
// ---------------------------------------------------------------------------
__global__ __launch_bounds__(256, 6) void sample_lds(
    const float* __restrict__ pts, const ushort_t* __restrict__ grid_t,
    const uint* __restrict__ order, const uint* __restrict__ bin_count,
    float* __restrict__ out)
{
    __shared__ __align__(16) ushort_t brick[BRICK_VOX * CCH];   // 21,600 B

    // XCD-chunked swizzle (16384 = 8 * 2048, bijective): x-adjacent bricks
    // (shared halo lines) stay on one XCD's L2.
    const int b  = (blockIdx.x & 7) * 2048 + (blockIdx.x >> 3);
    const int bx = b & 15, by = (b >> 4) & 31, bz = b >> 9;

    const uint cnt = min(bin_count[b], (uint)SLOTS);
    const uint start = (uint)b * SLOTS;
    const int t = threadIdx.x;
    const int sub = t & 1;

    // Hoist first point's loads above staging (latency hides under staging)
    uint ii = (uint)(t >> 1);
    int n0 = -1;
    float p0x = 0.f, p0y = 0.f, p0z = 0.f;
    if (ii < cnt) {
        n0 = (int)order[start + ii];
        p0x = pts[n0*3+0]; p0y = pts[n0*3+1]; p0z = pts[n0*3+2];
    }

    // ---- stage: 225 voxels * 6 uint4 = 1350 uint4, coalesced (864B rows) ----
    {
        uint4* bl = reinterpret_cast<uint4*>(brick);
        const uint4* gsrc = reinterpret_cast<const uint4*>(grid_t);
#pragma unroll
        for (int it = 0; it < 6; ++it) {
            const int i = it * 256 + t;
            if (i < BRICK_VOX * 6) {
                const int v = i / 6, p = i % 6;
                const int lz = v / 45, rem = v % 45, ly = rem / 9, lx = rem % 9;
                const int gz = min(bz*4 + lz, DD-1);
                const int gy = min(by*4 + ly, HH-1);
                const int gx = min(bx*8 + lx, WW-1);
                bl[v*6 + p] = gsrc[(size_t)((gz*HH + gy)*WW + gx) * 6 + p];
            }
        }
    }
    __syncthreads();
    if (cnt == 0) return;

    const uint4* bl = reinterpret_cast<const uint4*>(brick);
    int n = n0; float px = p0x, py = p0y, pz = p0z;
    for (; ii < cnt; ) {
        const PtGeo g = pt_geo3(px, py, pz);
        const float wx0 = 1.0f - g.wx, wy0 = 1.0f - g.wy, wz0 = 1.0f - g.wz;

        const int lx0 = g.x0 - bx*8, lx1 = g.x1 - bx*8;
        const int ly0 = g.y0 - by*4, ly1 = g.y1 - by*4;
        const int lz0 = g.z0 - bz*4, lz1 = g.z1 - bz*4;

        const int r0 = lz0*45, r1 = lz1*45;
        const int s0 = ly0*9,  s1 = ly1*9;
        const int vox[8] = { r0+s0+lx0, r0+s0+lx1, r0+s1+lx0, r0+s1+lx1,
                             r1+s0+lx0, r1+s0+lx1, r1+s1+lx0, r1+s1+lx1 };
        const float w[8] = { wx0*wy0*wz0,  g.wx*wy0*wz0,  wx0*g.wy*wz0,  g.wx*g.wy*wz0,
                             wx0*wy0*g.wz, g.wx*wy0*g.wz, wx0*g.wy*g.wz, g.wx*g.wy*g.wz };

        float acc[3][8];
#pragma unroll
        for (int j = 0; j < 3; ++j)
#pragma unroll
            for (int q = 0; q < 8; ++q) acc[j][q] = 0.0f;

        // 4 batches of 2 corners (6 uint4 live = 24 VGPR) — keeps us under
        // the 85-VGPR cap of launch_bounds(256,6)
#pragma unroll
        for (int half = 0; half < 4; ++half) {
            uint4 L[2][3];
#pragma unroll
            for (int c = 0; c < 2; ++c)
#pragma unroll
                for (int j = 0; j < 3; ++j)
                    L[c][j] = bl[vox[half*2 + c]*6 + 2*j + sub];
#pragma unroll
            for (int c = 0; c < 2; ++c) {
                const float wc = w[half*2 + c];
#pragma unroll
                for (int j = 0; j < 3; ++j) {
                    const uint* us = reinterpret_cast<const uint*>(&L[c][j]);
#pragma unroll
                    for (int q = 0; q < 4; ++q) {
                        acc[j][2*q]   = fmaf(wc, __uint_as_float(us[q] << 16),         acc[j][2*q]);
                        acc[j][2*q+1] = fmaf(wc, __uint_as_float(us[q] & 0xffff0000u), acc[j][2*q+1]);
                    }
                }
            }
        }

        float4* o = reinterpret_cast<float4*>(out + (size_t)n * CCH);
#pragma unroll
        for (int j = 0; j < 3; ++j) {
            const int gidx = 2*j + sub;
            o[2*gidx+0] = make_float4(acc[j][0], acc[j][1], acc[j][2], acc[j][3]);
            o[2*gidx+1] = make_float4(acc[j][4], acc[j][5], acc[j][6], acc[j][7]);
        }

        ii += 128;
        if (ii < cnt) {
            n = (int)order[start + ii];
            px = pts[n*3+0]; py = pts[n*3+1]; pz = pts[n*3+2];
        }
    }
}

// Overflow points (rare): direct gather from grid_t, same FMA order as
// sample_lds so values are bit-identical. Grid-strided, count read on device.
__global__ __launch_bounds__(256) void sample_ovf(
    const float* __restrict__ pts, const ushort_t* __restrict__ grid_t,
    const uint* __restrict__ ovf, const uint* __restrict__ ovf_cnt,
    float* __restrict__ out)
{
    const uint m = min(*ovf_cnt, (uint)OVF_CAP);
    for (uint i = blockIdx.x * 256 + threadIdx.x; i < m; i += 32 * 256) {
        const int n = (int)ovf[i];
        const PtGeo g = pt_geo(pts, n);
        const float wx0 = 1.0f - g.wx, wy0 = 1.0f - g.wy, wz0 = 1.0f - g.wz;
        const int HWn = HH*WW;
        const int vox[8] = { (g.z0*HWn + g.y0*WW + g.x0), (g.z0*HWn + g.y0*WW + g.x1),
                             (g.z0*HWn + g.y1*WW + g.x0), (g.z0*HWn + g.y1*WW + g.x1),
                             (g.z1*HWn + g.y0*WW + g.x0), (g.z1*HWn + g.y0*WW + g.x1),
                             (g.z1*HWn + g.y1*WW + g.x0), (g.z1*HWn + g.y1*WW + g.x1) };
        const float w[8] = { wx0*wy0*wz0,  g.wx*wy0*wz0,  wx0*g.wy*wz0,  g.wx*g.wy*wz0,
                             wx0*wy0*g.wz, g.wx*wy0*g.wz, wx0*g.wy*g.wz, g.wx*g.wy*g.wz };
        // per 8-channel chunk p: corners in same order as sample_lds
        for (int p = 0; p < 6; ++p) {
            float acc[8];
#pragma unroll
            for (int q = 0; q < 8; ++q) acc[q] = 0.0f;
#pragma unroll
            for (int c = 0; c < 8; ++c) {
                const uint4 u = reinterpret_cast<const uint4*>(grid_t)[(size_t)vox[c]*6 + p];
                const uint us[4] = {u.x, u.y, u.z, u.w};
                const float wc = w[c];
#pragma unroll
                for (int q = 0; q < 4; ++q) {
                    acc[2*q]   = fmaf(wc, __uint_as_float(us[q] << 16),         acc[2*q]);
                    acc[2*q+1] = fmaf(wc, __uint_as_float(us[q] & 0xffff0000u), acc[2*q+1]);
                }
            }
            float4* o = reinterpret_cast<float4*>(out + (size_t)n * CCH + p*8);
            o[0] = make_float4(acc[0], acc[1], acc[2], acc[3]);
            o[1] = make_float4(acc[4], acc[5], acc[6], acc[7]);
        }
    }
}

// Flat fallback (ws fits only grid_t).
__global__ __launch_bounds__(256) void sample_flat(
    const float* __restrict__ pts, const ushort_t* __restrict__ grid_t,
    float* __restrict__ out)
{
    const int tid = blockIdx.x * 256 + threadIdx.x;
    const int n   = tid >> 1;
    const int sub = tid & 1;

    const PtGeo g = pt_geo(pts, n);
    const float wx0 = 1.0f - g.wx, wy0 = 1.0f - g.wy, wz0 = 1.0f - g.wz;
    const int HWn = HH*WW;
    const int vox[8] = { (g.z0*HWn + g.y0*WW + g.x0), (g.z0*HWn + g.y0*WW + g.x1),
                         (g.z0*HWn + g.y1*WW + g.x0), (g.z0*HWn + g.y1*WW + g.x1),
                         (g.z1*HWn + g.y0*WW + g.x0), (g.z1*HWn + g.y0*WW + g.x1),
                         (g.z1*HWn + g.y1*WW + g.x0), (g.z1*HWn + g.y1*WW + g.x1) };
    const float w[8] = { wx0*wy0*wz0,  g.wx*wy0*wz0,  wx0*g.wy*wz0,  g.wx*g.wy*wz0,
                         wx0*wy0*g.wz, g.wx*wy0*g.wz, wx0*g.wy*g.wz, g.wx*g.wy*g.wz };

    uint4 L[8][3];
#pragma unroll
    for (int c = 0; c < 8; ++c) {
        const uint4* p = reinterpret_cast<const uint4*>(grid_t + (size_t)vox[c] * CCH);
#pragma unroll
        for (int j = 0; j < 3; ++j) L[c][j] = p[2*j + sub];
    }
    float acc[3][8];
#pragma unroll
    for (int j = 0; j < 3; ++j)
#pragma unroll
        for (int q = 0; q < 8; ++q) acc[j][q] = 0.0f;
#pragma unroll
    for (int c = 0; c < 8; ++c) {
        const float wc = w[c];
#pragma unroll
        for (int j = 0; j < 3; ++j) {
            const uint* us = reinterpret_cast<const uint*>(&L[c][j]);
#pragma unroll
            for (int q = 0; q < 4; ++q) {
                acc[j][2*q]   = fmaf(wc, __uint_as_float(us[q] << 16),         acc[j][2*q]);
                acc[j][2*q+1] = fmaf(wc, __uint_as_float(us[q] & 0xffff0000u), acc[j][2*q+1]);
            }
        }
    }
    float4* o = reinterpret_cast<float4*>(out + (size_t)n * CCH);
#pragma unroll
    for (int j = 0; j < 3; ++j) {
        const int gidx = 2*j + sub;
        o[2*gidx+0] = make_float4(acc[j][0], acc[j][1], acc[j][2], acc[j][3]);
        o[2*gidx+1] = make_float4(acc[j][4], acc[j][5], acc[j][6], acc[j][7]);
    }
}

// Last-resort fallback: direct f32 gather.
__global__ __launch_bounds__(256) void sample_naive(
    const float* __restrict__ pts, const float* __restrict__ k0,
    const float* __restrict__ former, float* __restrict__ out)
{
    const int n = blockIdx.x * 256 + threadIdx.x;
    if (n >= NPTS) return;
    const PtGeo g = pt_geo(pts, n);
    const float wx0 = 1.0f - g.wx, wy0 = 1.0f - g.wy, wz0 = 1.0f - g.wz;
    const int HWn = HH*WW;
    const int v000 = g.z0*HWn + g.y0*WW + g.x0, v100 = g.z0*HWn + g.y0*WW + g.x1;
    const int v010 = g.z0*HWn + g.y1*WW + g.x0, v110 = g.z0*HWn + g.y1*WW + g.x1;
    const int v001 = g.z1*HWn + g.y0*WW + g.x0, v101 = g.z1*HWn + g.y0*WW + g.x1;
    const int v011 = g.z1*HWn + g.y1*WW + g.x0, v111 = g.z1*HWn + g.y1*WW + g.x1;
    const float w000 = wx0*wy0*wz0,  w100 = g.wx*wy0*wz0;
    const float w010 = wx0*g.wy*wz0, w110 = g.wx*g.wy*wz0;
    const float w001 = wx0*wy0*g.wz, w101 = g.wx*wy0*g.wz;
    const float w011 = wx0*g.wy*g.wz, w111 = g.wx*g.wy*g.wz;
    for (int c = 0; c < CCH; ++c) {
        const float* g0 = k0     + (size_t)c * NVOX;
        const float* g1 = former + (size_t)c * NVOX;
        float s = 0.0f;
        s += w000 * (g0[v000] + g1[v000]);
        s += w100 * (g0[v100] + g1[v100]);
        s += w010 * (g0[v010] + g1[v010]);
        s += w110 * (g0[v110] + g1[v110]);
        s += w001 * (g0[v001] + g1[v001]);
        s += w101 * (g0[v101] + g1[v101]);
        s += w011 * (g0[v011] + g1[v011]);
        s += w111 * (g0[v111] + g1[v111]);
        out[(size_t)n*CCH + c] = s;
    }
}

extern "C" void kernel_launch(void* const* d_in, const int* in_sizes, int n_in,
                              void* d_out, int out_size, void* d_ws, size_t ws_size,
                              hipStream_t stream) {
    const float* ray_pts = (const float*)d_in[0];
    const float* k0      = (const float*)d_in[1];
    const float* former  = (const float*)d_in[2];
    float* out = (float*)d_out;

    const size_t grid_bytes  = (size_t)NVOX * CCH * sizeof(ushort_t);   // 201,326,592
    const size_t order_bytes = (size_t)NBINS * SLOTS * sizeof(uint);    //  10,485,760
    const size_t count_bytes = (size_t)NBINS * sizeof(uint);            //      65,536
    const size_t ovf_bytes   = (size_t)OVF_CAP * sizeof(uint);          //     262,144
    const size_t need_binned = grid_bytes + order_bytes + count_bytes + 64 + ovf_bytes;

    if (ws_size >= grid_bytes) {
        ushort_t* grid_t = (ushort_t*)d_ws;
        fuse_transpose_kernel<<<NVOX/256, 256, 0, stream>>>(k0, former, grid_t);
        if (ws_size >= need_binned) {
            char* p = (char*)d_ws + grid_bytes;
            uint* order   = (uint*)p;                 p += order_bytes;
            uint* count   = (uint*)p;                 p += count_bytes;
            uint* ovf_cnt = (uint*)p;                 p += 64;
            uint* ovf     = (uint*)p;
            hipMemsetAsync(count, 0, count_bytes + 64, stream);
            scatter_direct<<<NPTS/256, 256, 0, stream>>>(ray_pts, count, order, ovf_cnt, ovf);
            sample_lds    <<<NBINS, 256, 0, stream>>>(ray_pts, grid_t, order, count, out);
            sample_ovf    <<<32, 256, 0, stream>>>(ray_pts, grid_t, ovf, ovf_cnt, out);
        } else {
            sample_flat<<<(NPTS*2)/256, 256, 0, stream>>>(ray_pts, grid_t, out);
        }
    } else {
        sample_naive<<<NPTS/256, 256, 0, stream>>>(ray_pts, k0, former, out);
    }
}

// Round 9
// 702.808 us; speedup vs baseline: 2.2203x; 2.2203x over previous
//
#include <hip/hip_runtime.h>
#include <hip/hip_bf16.h>
#include <cstdint>

#define CCH 48
#define DD 128
#define HH 128
#define WW 128
#define NVOX (DD*HH*WW)        // 2,097,152 voxels
#define NPTS 2097152
// Bricks: 8x4x4 voxels (x,y,z); halo 9x5x5 = 225 voxels (21,600 B LDS)
#define NBINS 16384            // bx:16, by:32, bz:32
#define BRICK_VOX 225
#define TVOX 128               // voxels per transpose block

typedef unsigned int uint;
typedef unsigned short ushort_t;

__device__ __forceinline__ ushort_t f2bf_rne(float f) {
    uint u = __float_as_uint(f);
    uint r = (u + 0x7fffu + ((u >> 16) & 1u)) >> 16;
    return (ushort_t)r;
}

struct PtGeo {
    int x0, y0, z0, x1, y1, z1;
    float wx, wy, wz;
};
__device__ __forceinline__ PtGeo pt_geo3(float px, float py, float pz) {
    PtGeo g;
    const float ix = (px + 1.0f) * 63.5f;
    const float iy = (py + 1.0f) * 63.5f;
    const float iz = (pz + 1.0f) * 63.5f;
    const float xf = floorf(ix), yf = floorf(iy), zf = floorf(iz);
    g.wx = ix - xf; g.wy = iy - yf; g.wz = iz - zf;
    int x0 = (int)xf, y0 = (int)yf, z0 = (int)zf;
    g.x0 = min(max(x0,0), WW-1); g.x1 = min(max(x0+1,0), WW-1);
    g.y0 = min(max(y0,0), HH-1); g.y1 = min(max(y0+1,0), HH-1);
    g.z0 = min(max(z0,0), DD-1); g.z1 = min(max(z0+1,0), DD-1);
    return g;
}
__device__ __forceinline__ PtGeo pt_geo(const float* __restrict__ pts, int n) {
    return pt_geo3(pts[n*3+0], pts[n*3+1], pts[n*3+2]);
}
// brick 8x4x4: bin = ((bz*32)+by)*16 + bx
__device__ __forceinline__ int pt_bin(const PtGeo& g) {
    return (((g.z0 >> 2) * 32 + (g.y0 >> 2)) * 16) + (g.x0 >> 3);
}

// ---------------------------------------------------------------------------
// Kernel 1 v4: 2 threads/voxel (24 ch each), LDS-staged COALESCED stores.
// Reads: per instr 64 consecutive f32 (256B). Writes: 3 x 1KB/wave fully
// coalesced (fixes R1's 96B-stride 64-segment store pattern).
// ---------------------------------------------------------------------------
__global__ __launch_bounds__(256) void fuse_transpose_kernel(
    const float* __restrict__ k0, const float* __restrict__ former,
    ushort_t* __restrict__ grid_t)
{
    __shared__ __align__(16) uint4 st[TVOX * 6];    // 12,288 B
    const int t    = threadIdx.x;
    const int vx   = t & (TVOX-1);
    const int half = t >> 7;                        // 0: ch 0-23, 1: ch 24-47
    const size_t v = (size_t)blockIdx.x * TVOX + vx;

    float vals[24];
#pragma unroll
    for (int k = 0; k < 24; ++k) {
        const size_t off = (size_t)(half*24 + k) * NVOX + v;
        vals[k] = k0[off] + former[off];
    }
#pragma unroll
    for (int i = 0; i < 3; ++i) {
        uint4 u;
        u.x = (uint)f2bf_rne(vals[i*8+0]) | ((uint)f2bf_rne(vals[i*8+1]) << 16);
        u.y = (uint)f2bf_rne(vals[i*8+2]) | ((uint)f2bf_rne(vals[i*8+3]) << 16);
        u.z = (uint)f2bf_rne(vals[i*8+4]) | ((uint)f2bf_rne(vals[i*8+5]) << 16);
        u.w = (uint)f2bf_rne(vals[i*8+6]) | ((uint)f2bf_rne(vals[i*8+7]) << 16);
        st[vx*6 + half*3 + i] = u;
    }
    __syncthreads();
    uint4* dst = reinterpret_cast<uint4*>(grid_t) + (size_t)blockIdx.x * (TVOX*6);
#pragma unroll
    for (int i = 0; i < 3; ++i)
        dst[i*256 + t] = st[i*256 + t];
}

// ---------------------------------------------------------------------------
// 3-pass binning (R5/R6 structure — PROVEN deterministic across graph
// replays; R8's single-pass+overflow diverged post-timing, abandoned).
// ---------------------------------------------------------------------------
__global__ __launch_bounds__(256) void count_kernel(
    const float* __restrict__ pts, uint* __restrict__ count)
{
    const int n = blockIdx.x * 256 + threadIdx.x;
    if (n >= NPTS) return;
    const PtGeo g = pt_geo(pts, n);
    atomicAdd(&count[pt_bin(g)], 1u);
}

// 1 block x 1024 threads: exclusive scan of 16384 counts (16 per thread)
__global__ __launch_bounds__(1024) void scan_kernel(
    const uint* __restrict__ count, uint* __restrict__ cursor)
{
    __shared__ uint part[1024];
    const int t = threadIdx.x;
    uint c[16]; uint s = 0u;
#pragma unroll
    for (int k = 0; k < 16; ++k) { c[k] = count[t*16+k]; s += c[k]; }
    part[t] = s;
    __syncthreads();
    for (int off = 1; off < 1024; off <<= 1) {
        uint v = (t >= off) ? part[t-off] : 0u;
        __syncthreads();
        part[t] += v;
        __syncthreads();
    }
    uint ex = part[t] - s;
#pragma unroll
    for (int k = 0; k < 16; ++k) { cursor[t*16+k] = ex; ex += c[k]; }
}

__global__ __launch_bounds__(256) void scatter_kernel(
    const float* __restrict__ pts, uint* __restrict__ cursor, uint* __restrict__ order)
{
    const int n = blockIdx.x * 256 + threadIdx.x;
    if (n >= NPTS) return;
    const PtGeo g = pt_geo(pts, n);
    const uint pos = atomicAdd(&cursor[pt_bin(g)], 1u);
    order[pos] = (uint)n;
}

// ---------------------------------------------------------------------------
// Kernel 2: one block per 8x4x4 bin. 21,600 B LDS halo brick (LDS cap: 7
// blocks/CU), 2 lanes/point, 2-corner load batches (live set ~85-95 VGPR —
// natural, NO launch_bounds wave-cap per R2/R7 spill lesson).
// ---------------------------------------------------------------------------
__global__ __launch_bounds__(256) void sample_lds(
    const float* __restrict__ pts, const ushort_t* __restrict__ grid_t,
    const uint* __restrict__ order, const uint* __restrict__ bin_count,
    const uint* __restrict__ bin_end, float* __restrict__ out)
{
    __shared__ __align__(16) ushort_t brick[BRICK_VOX * CCH];   // 21,600 B

    // XCD-chunked swizzle (16384 = 8 * 2048, bijective)
    const int b  = (blockIdx.x & 7) * 2048 + (blockIdx.x >> 3);
    const int bx = b & 15, by = (b >> 4) & 31, bz = b >> 9;

    const uint cnt   = bin_count[b];
    const uint end   = bin_end[b];
    const uint start = end - cnt;

    // ---- stage: 225 voxels * 6 uint4 = 1350 uint4, coalesced (864B rows) ----
    const int t = threadIdx.x;
    {
        uint4* bl = reinterpret_cast<uint4*>(brick);
        const uint4* gsrc = reinterpret_cast<const uint4*>(grid_t);
#pragma unroll
        for (int it = 0; it < 6; ++it) {
            const int i = it * 256 + t;
            if (i < BRICK_VOX * 6) {
                const int v = i / 6, p = i % 6;
                const int lz = v / 45, rem = v % 45, ly = rem / 9, lx = rem % 9;
                const int gz = min(bz*4 + lz, DD-1);
                const int gy = min(by*4 + ly, HH-1);
                const int gx = min(bx*8 + lx, WW-1);
                bl[v*6 + p] = gsrc[(size_t)((gz*HH + gy)*WW + gx) * 6 + p];
            }
        }
    }
    __syncthreads();
    if (cnt == 0) return;

    const uint4* bl = reinterpret_cast<const uint4*>(brick);
    const int sub = t & 1;
    for (uint base = 0; base < cnt; base += 128) {
        const uint ii = base + (uint)(t >> 1);
        if (ii >= cnt) break;                   // no barriers below: safe
        const int n = (int)order[start + ii];

        const PtGeo g = pt_geo(pts, n);
        const float wx0 = 1.0f - g.wx, wy0 = 1.0f - g.wy, wz0 = 1.0f - g.wz;

        const int lx0 = g.x0 - bx*8, lx1 = g.x1 - bx*8;
        const int ly0 = g.y0 - by*4, ly1 = g.y1 - by*4;
        const int lz0 = g.z0 - bz*4, lz1 = g.z1 - bz*4;

        const int r0 = lz0*45, r1 = lz1*45;
        const int s0 = ly0*9,  s1 = ly1*9;
        const int vox[8] = { r0+s0+lx0, r0+s0+lx1, r0+s1+lx0, r0+s1+lx1,
                             r1+s0+lx0, r1+s0+lx1, r1+s1+lx0, r1+s1+lx1 };
        const float w[8] = { wx0*wy0*wz0,  g.wx*wy0*wz0,  wx0*g.wy*wz0,  g.wx*g.wy*wz0,
                             wx0*wy0*g.wz, g.wx*wy0*g.wz, wx0*g.wy*g.wz, g.wx*g.wy*g.wz };

        float acc[3][8];
#pragma unroll
        for (int j = 0; j < 3; ++j)
#pragma unroll
            for (int q = 0; q < 8; ++q) acc[j][q] = 0.0f;

        // 4 batches of 2 corners: 6 uint4 in flight, low live-register count.
        // Per-acc corner accumulation order stays 0..7 ascending.
#pragma unroll
        for (int quarter = 0; quarter < 4; ++quarter) {
            uint4 L[2][3];
#pragma unroll
            for (int c = 0; c < 2; ++c)
#pragma unroll
                for (int j = 0; j < 3; ++j)
                    L[c][j] = bl[vox[quarter*2 + c]*6 + 2*j + sub];
#pragma unroll
            for (int c = 0; c < 2; ++c) {
                const float wc = w[quarter*2 + c];
#pragma unroll
                for (int j = 0; j < 3; ++j) {
                    const uint* us = reinterpret_cast<const uint*>(&L[c][j]);
#pragma unroll
                    for (int q = 0; q < 4; ++q) {
                        acc[j][2*q]   = fmaf(wc, __uint_as_float(us[q] << 16),         acc[j][2*q]);
                        acc[j][2*q+1] = fmaf(wc, __uint_as_float(us[q] & 0xffff0000u), acc[j][2*q+1]);
                    }
                }
            }
        }

        float4* o = reinterpret_cast<float4*>(out + (size_t)n * CCH);
#pragma unroll
        for (int j = 0; j < 3; ++j) {
            const int gidx = 2*j + sub;
            o[2*gidx+0] = make_float4(acc[j][0], acc[j][1], acc[j][2], acc[j][3]);
            o[2*gidx+1] = make_float4(acc[j][4], acc[j][5], acc[j][6], acc[j][7]);
        }
    }
}

// Flat fallback (ws fits only grid_t).
__global__ __launch_bounds__(256) void sample_flat(
    const float* __restrict__ pts, const ushort_t* __restrict__ grid_t,
    float* __restrict__ out)
{
    const int tid = blockIdx.x * 256 + threadIdx.x;
    const int n   = tid >> 1;
    const int sub = tid & 1;

    const PtGeo g = pt_geo(pts, n);
    const float wx0 = 1.0f - g.wx, wy0 = 1.0f - g.wy, wz0 = 1.0f - g.wz;
    const int HWn = HH*WW;
    const int vox[8] = { (g.z0*HWn + g.y0*WW + g.x0), (g.z0*HWn + g.y0*WW + g.x1),
                         (g.z0*HWn + g.y1*WW + g.x0), (g.z0*HWn + g.y1*WW + g.x1),
                         (g.z1*HWn + g.y0*WW + g.x0), (g.z1*HWn + g.y0*WW + g.x1),
                         (g.z1*HWn + g.y1*WW + g.x0), (g.z1*HWn + g.y1*WW + g.x1) };
    const float w[8] = { wx0*wy0*wz0,  g.wx*wy0*wz0,  wx0*g.wy*wz0,  g.wx*g.wy*wz0,
                         wx0*wy0*g.wz, g.wx*wy0*g.wz, wx0*g.wy*g.wz, g.wx*g.wy*g.wz };

    uint4 L[8][3];
#pragma unroll
    for (int c = 0; c < 8; ++c) {
        const uint4* p = reinterpret_cast<const uint4*>(grid_t + (size_t)vox[c] * CCH);
#pragma unroll
        for (int j = 0; j < 3; ++j) L[c][j] = p[2*j + sub];
    }
    float acc[3][8];
#pragma unroll
    for (int j = 0; j < 3; ++j)
#pragma unroll
        for (int q = 0; q < 8; ++q) acc[j][q] = 0.0f;
#pragma unroll
    for (int c = 0; c < 8; ++c) {
        const float wc = w[c];
#pragma unroll
        for (int j = 0; j < 3; ++j) {
            const uint* us = reinterpret_cast<const uint*>(&L[c][j]);
#pragma unroll
            for (int q = 0; q < 4; ++q) {
                acc[j][2*q]   = fmaf(wc, __uint_as_float(us[q] << 16),         acc[j][2*q]);
                acc[j][2*q+1] = fmaf(wc, __uint_as_float(us[q] & 0xffff0000u), acc[j][2*q+1]);
            }
        }
    }
    float4* o = reinterpret_cast<float4*>(out + (size_t)n * CCH);
#pragma unroll
    for (int j = 0; j < 3; ++j) {
        const int gidx = 2*j + sub;
        o[2*gidx+0] = make_float4(acc[j][0], acc[j][1], acc[j][2], acc[j][3]);
        o[2*gidx+1] = make_float4(acc[j][4], acc[j][5], acc[j][6], acc[j][7]);
    }
}

// Last-resort fallback: direct f32 gather.
__global__ __launch_bounds__(256) void sample_naive(
    const float* __restrict__ pts, const float* __restrict__ k0,
    const float* __restrict__ former, float* __restrict__ out)
{
    const int n = blockIdx.x * 256 + threadIdx.x;
    if (n >= NPTS) return;
    const PtGeo g = pt_geo(pts, n);
    const float wx0 = 1.0f - g.wx, wy0 = 1.0f - g.wy, wz0 = 1.0f - g.wz;
    const int HWn = HH*WW;
    const int v000 = g.z0*HWn + g.y0*WW + g.x0, v100 = g.z0*HWn + g.y0*WW + g.x1;
    const int v010 = g.z0*HWn + g.y1*WW + g.x0, v110 = g.z0*HWn + g.y1*WW + g.x1;
    const int v001 = g.z1*HWn + g.y0*WW + g.x0, v101 = g.z1*HWn + g.y0*WW + g.x1;
    const int v011 = g.z1*HWn + g.y1*WW + g.x0, v111 = g.z1*HWn + g.y1*WW + g.x1;
    const float w000 = wx0*wy0*wz0,  w100 = g.wx*wy0*wz0;
    const float w010 = wx0*g.wy*wz0, w110 = g.wx*g.wy*wz0;
    const float w001 = wx0*wy0*g.wz, w101 = g.wx*wy0*g.wz;
    const float w011 = wx0*g.wy*g.wz, w111 = g.wx*g.wy*g.wz;
    for (int c = 0; c < CCH; ++c) {
        const float* g0 = k0     + (size_t)c * NVOX;
        const float* g1 = former + (size_t)c * NVOX;
        float s = 0.0f;
        s += w000 * (g0[v000] + g1[v000]);
        s += w100 * (g0[v100] + g1[v100]);
        s += w010 * (g0[v010] + g1[v010]);
        s += w110 * (g0[v110] + g1[v110]);
        s += w001 * (g0[v001] + g1[v001]);
        s += w101 * (g0[v101] + g1[v101]);
        s += w011 * (g0[v011] + g1[v011]);
        s += w111 * (g0[v111] + g1[v111]);
        out[(size_t)n*CCH + c] = s;
    }
}

extern "C" void kernel_launch(void* const* d_in, const int* in_sizes, int n_in,
                              void* d_out, int out_size, void* d_ws, size_t ws_size,
                              hipStream_t stream) {
    const float* ray_pts = (const float*)d_in[0];
    const float* k0      = (const float*)d_in[1];
    const float* former  = (const float*)d_in[2];
    float* out = (float*)d_out;

    const size_t grid_bytes  = (size_t)NVOX * CCH * sizeof(ushort_t);   // 201,326,592
    const size_t order_bytes = (size_t)NPTS * sizeof(uint);             //   8,388,608
    const size_t bins_bytes  = (size_t)NBINS * sizeof(uint);            //      65,536
    const size_t need_binned = grid_bytes + order_bytes + 2*bins_bytes; // 209,846,272

    if (ws_size >= grid_bytes) {
        ushort_t* grid_t = (ushort_t*)d_ws;
        fuse_transpose_kernel<<<NVOX/TVOX, 256, 0, stream>>>(k0, former, grid_t);
        if (ws_size >= need_binned) {
            char* p = (char*)d_ws + grid_bytes;
            uint* order  = (uint*)p;                 p += order_bytes;
            uint* count  = (uint*)p;                 p += bins_bytes;
            uint* cursor = (uint*)p;
            hipMemsetAsync(count, 0, bins_bytes, stream);
            count_kernel  <<<NPTS/256, 256, 0, stream>>>(ray_pts, count);
            scan_kernel   <<<1, 1024, 0, stream>>>(count, cursor);
            scatter_kernel<<<NPTS/256, 256, 0, stream>>>(ray_pts, cursor, order);
            sample_lds    <<<NBINS, 256, 0, stream>>>(ray_pts, grid_t, order, count, cursor, out);
        } else {
            sample_flat<<<(NPTS*2)/256, 256, 0, stream>>>(ray_pts, grid_t, out);
        }
    } else {
        sample_naive<<<NPTS/256, 256, 0, stream>>>(ray_pts, k0, former, out);
    }
}